// Round 1
// baseline (290.462 us; speedup 1.0000x reference)
//
#include <hip/hip_runtime.h>
#include <hip/hip_bf16.h>
#include <cstddef>

#define NBATCH 16384
#define NNB 32
#define DD 128
#define NH 4
#define NHD 512   // NH * DD

// ---------------------------------------------------------------------------
// K0: precompute A_all[i][h*128+d] = sum_r Wq[h][r][i] * Wk[h][r][d]
//     and       C_all[h*128+i][o]  = 0.25 * sum_d Wo[o][d] * Wv[h][d][i]
// ---------------------------------------------------------------------------
__global__ __launch_bounds__(256) void precompute_kernel(
    const float* __restrict__ Wq, const float* __restrict__ Wk,
    const float* __restrict__ Wv, const float* __restrict__ Wo,
    float* __restrict__ AA, float* __restrict__ CC) {
  int e = blockIdx.x * 256 + threadIdx.x;   // 0..65535
  if (blockIdx.y == 0) {
    int i = e >> 9;            // 0..127
    int hd = e & 511;
    int h = hd >> 7, d = hd & 127;
    const float* wq = Wq + h * 16384;
    const float* wk = Wk + h * 16384;
    float acc = 0.f;
    #pragma unroll 8
    for (int r = 0; r < 128; ++r) acc += wq[r * 128 + i] * wk[r * 128 + d];
    AA[e] = acc;
  } else {
    int hi = e >> 7;           // 0..511
    int o = e & 127;
    int h = hi >> 7, i = hi & 127;
    const float* wv = Wv + h * 16384;
    float acc = 0.f;
    #pragma unroll 8
    for (int d = 0; d < 128; ++d) acc += Wo[o * 128 + d] * wv[d * 128 + i];
    CC[e] = 0.25f * acc;
  }
}

// ---------------------------------------------------------------------------
// K1: G[b][hd] = sum_i x[b][i] * AA[i][hd]
// thread-per-batch; x row in VGPRs; AA addresses are wave-uniform -> s_loads.
// grid (64, 8): blockIdx.y selects a 64-wide hd slice.
// ---------------------------------------------------------------------------
__global__ __launch_bounds__(256) void gemm1_kernel(
    const float* __restrict__ x, const float* __restrict__ AA,
    float* __restrict__ G) {
  const int b = blockIdx.x * 256 + threadIdx.x;
  const int hd0 = blockIdx.y * 64;
  float xr[128];
  const float4* xp = (const float4*)(x + (size_t)b * DD);
  #pragma unroll
  for (int i = 0; i < 32; ++i) {
    float4 v = xp[i];
    xr[4 * i + 0] = v.x; xr[4 * i + 1] = v.y;
    xr[4 * i + 2] = v.z; xr[4 * i + 3] = v.w;
  }
  for (int c0 = 0; c0 < 64; c0 += 8) {
    float acc[8] = {0.f, 0.f, 0.f, 0.f, 0.f, 0.f, 0.f, 0.f};
    #pragma unroll
    for (int i = 0; i < 128; ++i) {
      const float* ap = AA + i * NHD + hd0 + c0;
      #pragma unroll
      for (int c = 0; c < 8; ++c) acc[c] += xr[i] * ap[c];
    }
    float* gp = G + (size_t)b * NHD + hd0 + c0;
    #pragma unroll
    for (int c = 0; c < 8; ++c) gp[c] = acc[c];
  }
}

// ---------------------------------------------------------------------------
// K2: per-batch attention. One wave per batch, 4 waves/block.
//   logits[h][n] = sum_i g[h][i]*nb[n][i]; softmax over n;
//   WS[b][h*128+i] = sum_n attn[h][n]*nb[n][i]
// ---------------------------------------------------------------------------
__global__ __launch_bounds__(256) void attn_kernel(
    const float* __restrict__ nb, const float* __restrict__ G,
    float* __restrict__ WS) {
  __shared__ float g_lds[4][NHD];
  __shared__ float attn_lds[4][NH * NNB];
  const int wave = threadIdx.x >> 6;
  const int lane = threadIdx.x & 63;
  const int b = blockIdx.x * 4 + wave;

  // stage g row into LDS (coalesced)
  {
    const float4* gp = (const float4*)(G + (size_t)b * NHD);
    float4 g0 = gp[lane * 2 + 0];
    float4 g1 = gp[lane * 2 + 1];
    float4* dst = (float4*)&g_lds[wave][lane * 8];
    dst[0] = g0; dst[1] = g1;
  }

  const int n = lane & 31, half = lane >> 5;
  const float* nrow = nb + ((size_t)b * NNB + n) * DD + half * 64;
  float v[64];
  #pragma unroll
  for (int j = 0; j < 16; ++j) {
    float4 t = ((const float4*)nrow)[j];
    v[4 * j + 0] = t.x; v[4 * j + 1] = t.y;
    v[4 * j + 2] = t.z; v[4 * j + 3] = t.w;
  }

  float attv[NH];
  #pragma unroll
  for (int h = 0; h < NH; ++h) {
    const float* gh = &g_lds[wave][h * DD + half * 64];
    float p = 0.f;
    #pragma unroll
    for (int i = 0; i < 64; ++i) p += gh[i] * v[i];
    p += __shfl_xor(p, 32);   // combine halves; lanes (n, n+32) now equal
    attv[h] = p;
  }

  // softmax over the 32 n's (replicated identically in both halves)
  #pragma unroll
  for (int h = 0; h < NH; ++h) {
    float m = attv[h];
    #pragma unroll
    for (int off = 16; off >= 1; off >>= 1) m = fmaxf(m, __shfl_xor(m, off));
    float e = __expf(attv[h] - m);
    float s = e;
    #pragma unroll
    for (int off = 16; off >= 1; off >>= 1) s += __shfl_xor(s, off);
    attv[h] = e / s;
  }
  if (half == 0) {
    #pragma unroll
    for (int h = 0; h < NH; ++h) attn_lds[wave][h * NNB + n] = attv[h];
  }

  // weighted neighbor sum: lane owns columns (2*lane, 2*lane+1); nb re-read L2-hot
  float2 acc0 = {0.f, 0.f}, acc1 = {0.f, 0.f}, acc2 = {0.f, 0.f}, acc3 = {0.f, 0.f};
  const float* nbb = nb + (size_t)b * NNB * DD;
  #pragma unroll 4
  for (int n2 = 0; n2 < NNB; ++n2) {
    float2 f = *(const float2*)(nbb + n2 * DD + 2 * lane);
    float a0 = attn_lds[wave][0 * NNB + n2];
    float a1 = attn_lds[wave][1 * NNB + n2];
    float a2 = attn_lds[wave][2 * NNB + n2];
    float a3 = attn_lds[wave][3 * NNB + n2];
    acc0.x += a0 * f.x; acc0.y += a0 * f.y;
    acc1.x += a1 * f.x; acc1.y += a1 * f.y;
    acc2.x += a2 * f.x; acc2.y += a2 * f.y;
    acc3.x += a3 * f.x; acc3.y += a3 * f.y;
  }
  float* wsp = WS + (size_t)b * NHD;
  *(float2*)(wsp + 0 * DD + 2 * lane) = acc0;
  *(float2*)(wsp + 1 * DD + 2 * lane) = acc1;
  *(float2*)(wsp + 2 * DD + 2 * lane) = acc2;
  *(float2*)(wsp + 3 * DD + 2 * lane) = acc3;
}

// ---------------------------------------------------------------------------
// K3: OUT[b][o] = leaky_relu( sum_k WS[b][k]*CC[k][o] + bo[o] )
// 32-batch tile in LDS; thread computes 4 batches x 4 outputs.
// ---------------------------------------------------------------------------
__global__ __launch_bounds__(256) void gemm2_kernel(
    const float* __restrict__ WS, const float* __restrict__ CC,
    const float* __restrict__ bo, float* __restrict__ out) {
  __shared__ float ws_lds[32 * NHD];  // 64 KB
  const int bt0 = blockIdx.x * 32;
  {
    const float4* src = (const float4*)(WS + (size_t)bt0 * NHD);
    float4* dst = (float4*)ws_lds;
    #pragma unroll
    for (int t = 0; t < 16; ++t)
      dst[t * 256 + threadIdx.x] = src[t * 256 + threadIdx.x];
  }
  __syncthreads();

  const int tx = threadIdx.x & 31;   // output group
  const int ty = threadIdx.x >> 5;   // batch group (0..7)
  const int o0 = tx * 4;
  const int bat0 = ty * 4;
  float acc[4][4] = {};
  #pragma unroll 4
  for (int k = 0; k < NHD; ++k) {
    float4 c4 = *(const float4*)(CC + k * DD + o0);
    #pragma unroll
    for (int bb = 0; bb < 4; ++bb) {
      float w = ws_lds[(bat0 + bb) * NHD + k];
      acc[bb][0] += w * c4.x;
      acc[bb][1] += w * c4.y;
      acc[bb][2] += w * c4.z;
      acc[bb][3] += w * c4.w;
    }
  }
  float4 bias = *(const float4*)(bo + o0);
  #pragma unroll
  for (int bb = 0; bb < 4; ++bb) {
    float r0 = acc[bb][0] + bias.x;
    float r1 = acc[bb][1] + bias.y;
    float r2 = acc[bb][2] + bias.z;
    float r3 = acc[bb][3] + bias.w;
    float4 r;
    r.x = r0 > 0.f ? r0 : 0.01f * r0;
    r.y = r1 > 0.f ? r1 : 0.01f * r1;
    r.z = r2 > 0.f ? r2 : 0.01f * r2;
    r.w = r3 > 0.f ? r3 : 0.01f * r3;
    *(float4*)(out + (size_t)(bt0 + bat0 + bb) * DD + o0) = r;
  }
}

// ---------------------------------------------------------------------------
extern "C" void kernel_launch(void* const* d_in, const int* in_sizes, int n_in,
                              void* d_out, int out_size, void* d_ws, size_t ws_size,
                              hipStream_t stream) {
  const float* x  = (const float*)d_in[0];
  const float* nb = (const float*)d_in[1];
  const float* Wq = (const float*)d_in[2];
  const float* Wk = (const float*)d_in[3];
  const float* Wv = (const float*)d_in[4];
  const float* Wo = (const float*)d_in[5];
  const float* bo = (const float*)d_in[6];
  float* out = (float*)d_out;

  float* ws = (float*)d_ws;
  float* AA = ws;                                  // [128][512]
  float* CC = ws + 65536;                          // [512][128]
  float* G  = ws + 131072;                         // [B][512]
  float* WS = G + (size_t)NBATCH * NHD;            // [B][512]

  precompute_kernel<<<dim3(256, 2), 256, 0, stream>>>(Wq, Wk, Wv, Wo, AA, CC);
  gemm1_kernel<<<dim3(64, 8), 256, 0, stream>>>(x, AA, G);
  attn_kernel<<<dim3(NBATCH / 4), 256, 0, stream>>>(nb, G, WS);
  gemm2_kernel<<<dim3(NBATCH / 32), 256, 0, stream>>>(WS, CC, bo, out);
}

// Round 3
// 195.863 us; speedup vs baseline: 1.4830x; 1.4830x over previous
//
#include <hip/hip_runtime.h>
#include <hip/hip_bf16.h>
#include <cstddef>

#define NBATCH 16384
#define NNB 32
#define DD 128
#define NH 4
#define NHD 512   // NH * DD
#define BB 16     // batches per block
#define NT 512    // threads per block

// ---------------------------------------------------------------------------
// K0: precompute A_all[i][h*128+d] = sum_r Wq[h][r][i] * Wk[h][r][d]
//     and       C_all[h*128+i][o]  = 0.25 * sum_d Wo[o][d] * Wv[h][d][i]
// ---------------------------------------------------------------------------
__global__ __launch_bounds__(256) void precompute_kernel(
    const float* __restrict__ Wq, const float* __restrict__ Wk,
    const float* __restrict__ Wv, const float* __restrict__ Wo,
    float* __restrict__ AA, float* __restrict__ CC) {
  int e = blockIdx.x * 256 + threadIdx.x;   // 0..65535
  if (blockIdx.y == 0) {
    int i = e >> 9;            // 0..127
    int hd = e & 511;
    int h = hd >> 7, d = hd & 127;
    const float* wq = Wq + h * 16384;
    const float* wk = Wk + h * 16384;
    float acc = 0.f;
    #pragma unroll 8
    for (int r = 0; r < 128; ++r) acc += wq[r * 128 + i] * wk[r * 128 + d];
    AA[e] = acc;
  } else {
    int hi = e >> 7;           // 0..511
    int o = e & 127;
    int h = hi >> 7, i = hi & 127;
    const float* wv = Wv + h * 16384;
    float acc = 0.f;
    #pragma unroll 8
    for (int d = 0; d < 128; ++d) acc += Wo[o * 128 + d] * wv[d * 128 + i];
    CC[e] = 0.25f * acc;
  }
}

// ---------------------------------------------------------------------------
// Fused: gemm1 (g = x@AA) -> attention (logits/softmax/weighted-sum, nb read
// ONCE into registers, column-major per lane, butterfly reduction) ->
// gemm2 (out = ws@CC + bo, leaky). Block = 512 thr, 16 batches, 80 KB LDS.
// ---------------------------------------------------------------------------
__global__ __launch_bounds__(NT, 4) void fused_kernel(
    const float* __restrict__ x, const float* __restrict__ nb,
    const float* __restrict__ AA, const float* __restrict__ CC,
    const float* __restrict__ bo, float* __restrict__ out) {

  __shared__ __align__(16) float x_lds[BB][DD];        // 8 KB
  __shared__ __align__(16) float g_lds[BB][NHD];       // 32 KB (reused as partials)
  __shared__ __align__(16) float ws_lds[BB][NHD];      // 32 KB
  __shared__ __align__(16) float attn_lds[BB][NNB*NH]; // 8 KB

  const int t = threadIdx.x;
  const int b0 = blockIdx.x * BB;

  // ---- phase 0: stage x rows (16 x 128 = 512 float4, one per thread)
  {
    float4 v = ((const float4*)(x + (size_t)b0 * DD))[t];
    ((float4*)x_lds)[t] = v;
  }
  __syncthreads();

  // ---- phase 1: g[b][hd] = sum_i x[b][i] * AA[i][hd]
  {
    const int hdq = t & 127;   // hd = 4*hdq
    const int bq  = t >> 7;    // batches 4*bq .. 4*bq+3
    const float4* AA4 = (const float4*)AA;   // [128][128] float4
    float4 acc[4];
    #pragma unroll
    for (int j = 0; j < 4; ++j) acc[j] = make_float4(0.f, 0.f, 0.f, 0.f);
    #pragma unroll 2
    for (int i4 = 0; i4 < 128; i4 += 4) {
      float4 a0 = AA4[(i4 + 0) * 128 + hdq];
      float4 a1 = AA4[(i4 + 1) * 128 + hdq];
      float4 a2 = AA4[(i4 + 2) * 128 + hdq];
      float4 a3 = AA4[(i4 + 3) * 128 + hdq];
      #pragma unroll
      for (int j = 0; j < 4; ++j) {
        float4 xv = *(const float4*)&x_lds[4 * bq + j][i4];  // wave-uniform b128
        acc[j].x += xv.x * a0.x + xv.y * a1.x + xv.z * a2.x + xv.w * a3.x;
        acc[j].y += xv.x * a0.y + xv.y * a1.y + xv.z * a2.y + xv.w * a3.y;
        acc[j].z += xv.x * a0.z + xv.y * a1.z + xv.z * a2.z + xv.w * a3.z;
        acc[j].w += xv.x * a0.w + xv.y * a1.w + xv.z * a2.w + xv.w * a3.w;
      }
    }
    #pragma unroll
    for (int j = 0; j < 4; ++j)
      *(float4*)&g_lds[4 * bq + j][4 * hdq] = acc[j];
  }
  __syncthreads();

  // ---- phase 2: attention; wave owns 2 batches, nb in registers col-major
  {
    const int wv_ = t >> 6;      // wave 0..7
    const int lane = t & 63;
    // after the 5-step butterfly, lane holds n = bit-reversal(lane bits 0..4)
    const int nl = ((lane & 1) << 4) | ((lane & 2) << 2) | (lane & 4) |
                   ((lane & 8) >> 2) | ((lane & 16) >> 4);
    const int bit0 = lane & 1;
    #pragma unroll 1
    for (int c = 0; c < 2; ++c) {
      const int b = 2 * wv_ + c;
      const float* nbb = nb + ((size_t)(b0 + b)) * (NNB * DD);
      float v[64];   // lane owns columns 2*lane, 2*lane+1 for all 32 rows
      #pragma unroll
      for (int n = 0; n < 32; ++n) {
        float2 f = *(const float2*)(nbb + n * DD + 2 * lane);
        v[2 * n] = f.x; v[2 * n + 1] = f.y;
      }
      #pragma unroll
      for (int h = 0; h < NH; ++h) {
        float2 g2 = *(const float2*)&g_lds[b][h * DD + 2 * lane];
        // generate partials and fold in butterfly step 0 immediately (p: 16 regs)
        float p[16];
        #pragma unroll
        for (int k = 0; k < 16; ++k) {
          float plo = g2.x * v[2 * k]        + g2.y * v[2 * k + 1];
          float phi = g2.x * v[2 * (k + 16)] + g2.y * v[2 * (k + 16) + 1];
          float keep = bit0 ? phi : plo;
          float send = bit0 ? plo : phi;
          p[k] = keep + __shfl_xor(send, 1);
        }
        // butterfly steps 1..4: exchange the NOT-kept half, add to kept half
        #pragma unroll
        for (int s = 1; s < 5; ++s) {
          const int nsel = 16 >> s;
          const int bit = (lane >> s) & 1;
          #pragma unroll
          for (int k = 0; k < nsel; ++k) {
            float keep = bit ? p[k + nsel] : p[k];
            float send = bit ? p[k] : p[k + nsel];
            p[k] = keep + __shfl_xor(send, 1 << s);
          }
        }
        float tot = p[0] + __shfl_xor(p[0], 32);  // full 128-col logit for n=nl
        // softmax over 64 lanes (each n duplicated exactly twice)
        float m = tot;
        #pragma unroll
        for (int off = 32; off >= 1; off >>= 1)
          m = fmaxf(m, __shfl_xor(m, off));
        float e = __expf(tot - m);
        float s64 = e;
        #pragma unroll
        for (int off = 32; off >= 1; off >>= 1)
          s64 += __shfl_xor(s64, off);
        float attnv = e * 2.0f / s64;    // s64 counts each n twice
        attn_lds[b][nl * 4 + h] = attnv; // duplicate write (same value) benign
      }
      // weighted neighbor sum from the SAME registers (no nb re-read)
      float wsa[NH][2];
      #pragma unroll
      for (int h = 0; h < NH; ++h) { wsa[h][0] = 0.f; wsa[h][1] = 0.f; }
      #pragma unroll
      for (int n = 0; n < 32; ++n) {
        float4 a4 = *(const float4*)&attn_lds[b][n * 4];  // uniform broadcast
        wsa[0][0] += a4.x * v[2 * n]; wsa[0][1] += a4.x * v[2 * n + 1];
        wsa[1][0] += a4.y * v[2 * n]; wsa[1][1] += a4.y * v[2 * n + 1];
        wsa[2][0] += a4.z * v[2 * n]; wsa[2][1] += a4.z * v[2 * n + 1];
        wsa[3][0] += a4.w * v[2 * n]; wsa[3][1] += a4.w * v[2 * n + 1];
      }
      #pragma unroll
      for (int h = 0; h < NH; ++h)
        *(float2*)&ws_lds[b][h * DD + 2 * lane] = make_float2(wsa[h][0], wsa[h][1]);
    }
  }
  __syncthreads();

  // ---- phase 3: gemm2 partials, k split across 4 thread groups
  {
    const int oq = t & 31;         // o = 4*oq
    const int bq = (t >> 5) & 3;   // batches 4*bq .. 4*bq+3
    const int kg = t >> 7;         // k range kg*128 .. +127
    const float4* CC4 = (const float4*)CC;   // [512][32] float4
    float4 acc[4];
    #pragma unroll
    for (int j = 0; j < 4; ++j) acc[j] = make_float4(0.f, 0.f, 0.f, 0.f);
    const int kbase = kg * 128;
    #pragma unroll 2
    for (int kk = 0; kk < 128; kk += 4) {
      const int k = kbase + kk;
      float4 c0 = CC4[(k + 0) * 32 + oq];
      float4 c1 = CC4[(k + 1) * 32 + oq];
      float4 c2 = CC4[(k + 2) * 32 + oq];
      float4 c3 = CC4[(k + 3) * 32 + oq];
      #pragma unroll
      for (int j = 0; j < 4; ++j) {
        float4 w = *(const float4*)&ws_lds[4 * bq + j][k];  // 2-addr broadcast
        acc[j].x += w.x * c0.x + w.y * c1.x + w.z * c2.x + w.w * c3.x;
        acc[j].y += w.x * c0.y + w.y * c1.y + w.z * c2.y + w.w * c3.y;
        acc[j].z += w.x * c0.z + w.y * c1.z + w.z * c2.z + w.w * c3.z;
        acc[j].w += w.x * c0.w + w.y * c1.w + w.z * c2.w + w.w * c3.w;
      }
    }
    // partials into g_lds (dead after phase 2): [4 kg][16 b][128 o] = 32 KB
    float* part = (float*)g_lds;
    #pragma unroll
    for (int j = 0; j < 4; ++j)
      *(float4*)&part[((kg * BB) + (4 * bq + j)) * DD + 4 * oq] = acc[j];
  }
  __syncthreads();

  // ---- phase 4: reduce partials + bias + leaky relu + store
  {
    const int o4 = t & 31;
    const int b  = t >> 5;   // 0..15
    const float* part = (const float*)g_lds;
    float4 p0 = *(const float4*)&part[(0 * BB + b) * DD + 4 * o4];
    float4 p1 = *(const float4*)&part[(1 * BB + b) * DD + 4 * o4];
    float4 p2 = *(const float4*)&part[(2 * BB + b) * DD + 4 * o4];
    float4 p3 = *(const float4*)&part[(3 * BB + b) * DD + 4 * o4];
    float4 bias = ((const float4*)bo)[o4];
    float r0 = p0.x + p1.x + p2.x + p3.x + bias.x;
    float r1 = p0.y + p1.y + p2.y + p3.y + bias.y;
    float r2 = p0.z + p1.z + p2.z + p3.z + bias.z;
    float r3 = p0.w + p1.w + p2.w + p3.w + bias.w;
    float4 r;
    r.x = r0 > 0.f ? r0 : 0.01f * r0;
    r.y = r1 > 0.f ? r1 : 0.01f * r1;
    r.z = r2 > 0.f ? r2 : 0.01f * r2;
    r.w = r3 > 0.f ? r3 : 0.01f * r3;
    ((float4*)(out + (size_t)(b0 + b) * DD))[o4] = r;
  }
}

// ---------------------------------------------------------------------------
extern "C" void kernel_launch(void* const* d_in, const int* in_sizes, int n_in,
                              void* d_out, int out_size, void* d_ws, size_t ws_size,
                              hipStream_t stream) {
  const float* x  = (const float*)d_in[0];
  const float* nb = (const float*)d_in[1];
  const float* Wq = (const float*)d_in[2];
  const float* Wk = (const float*)d_in[3];
  const float* Wv = (const float*)d_in[4];
  const float* Wo = (const float*)d_in[5];
  const float* bo = (const float*)d_in[6];
  float* out = (float*)d_out;

  float* ws = (float*)d_ws;
  float* AA = ws;            // [128][512]
  float* CC = ws + 65536;    // [512][128]

  precompute_kernel<<<dim3(256, 2), 256, 0, stream>>>(Wq, Wk, Wv, Wo, AA, CC);
  fused_kernel<<<dim3(NBATCH / BB), NT, 0, stream>>>(x, nb, AA, CC, bo, out);
}